// Round 6
// baseline (25934.467 us; speedup 1.0000x reference)
//
#include <hip/hip_runtime.h>

#define T_STEPS 65536
#define NIN 99
#define HID 64
#define G4 256   // 4*HID gates
#define TS 128   // timesteps per block in the projection kernel
#define PF 8     // prefetch depth (steps) in the recurrence kernel

__device__ __forceinline__ float frcp(float x) { return __builtin_amdgcn_rcpf(x); }
__device__ __forceinline__ float fexp(float x) { return __expf(x); }
__device__ __forceinline__ float sigmoid_f(float x) { return frcp(1.0f + fexp(-x)); }
__device__ __forceinline__ float tanh_f(float x) {
    float ax = fabsf(x);
    float e  = fexp(2.0f * ax);                 // inf for large ax fine: rcp(inf)=0
    float r  = 1.0f - 2.0f * frcp(e + 1.0f);
    return copysignf(r, x);
}
// wave-uniform broadcast of lane `lane`'s value via readlane (VALU->SGPR)
__device__ __forceinline__ float bcast(float v, int lane) {
    return __int_as_float(__builtin_amdgcn_readlane(__float_as_int(v), lane));
}

// ---------------- Kernel 1: xz[t][g] = W_ih[g] . x[t] + b_ih[g] + b_hh[g] ----------------
__global__ __launch_bounds__(256, 1) void xz_kernel(
    const float* __restrict__ x, const float* __restrict__ W_ih,
    const float* __restrict__ b_ih, const float* __restrict__ b_hh,
    float* __restrict__ xz) {
    __shared__ __align__(16) float xs[TS * 100];   // padded rows: 400 B stride
    const int g  = threadIdx.x;
    const int t0 = blockIdx.x * TS;

    for (int i = g; i < TS * NIN; i += 256) {
        int tl = i / NIN;
        int j  = i - tl * NIN;
        xs[tl * 100 + j] = x[(size_t)t0 * NIN + i];
    }

    float w[NIN];
#pragma unroll
    for (int j = 0; j < NIN; ++j) w[j] = W_ih[g * NIN + j];
    const float bias = b_ih[g] + b_hh[g];
    __syncthreads();

    for (int tl = 0; tl < TS; ++tl) {
        const float* xr = &xs[tl * 100];
        float a0 = bias, a1 = 0.f, a2 = 0.f, a3 = 0.f;
#pragma unroll
        for (int j4 = 0; j4 < 24; ++j4) {
            float4 xv = *(const float4*)(xr + 4 * j4);
            a0 = fmaf(w[4 * j4 + 0], xv.x, a0);
            a1 = fmaf(w[4 * j4 + 1], xv.y, a1);
            a2 = fmaf(w[4 * j4 + 2], xv.z, a2);
            a3 = fmaf(w[4 * j4 + 3], xv.w, a3);
        }
        a0 = fmaf(w[96], xr[96], a0);
        a1 = fmaf(w[97], xr[97], a1);
        a2 = fmaf(w[98], xr[98], a2);
        xz[(size_t)(t0 + tl) * G4 + g] = (a0 + a1) + (a2 + a3);
    }
}

// ---------------- Kernel 2: split-K LSTM recurrence, ONE barrier/step ----------------
// Phase 1: wave wv owns k-chunk [16wv,16wv+16); thread (wv,l) computes partial
//   dots of gates 4l..4l+3 over its chunk (16 readlane + 64 fma), writes a
//   float4 to pbuf[par][wv].
// Barrier.
// Phase 2 (replicated in all waves): thread l reads the 16 partials of ITS
//   hidden unit (gates l,64+l,128+l,192+l across 4 chunks; stride-64 reads =
//   2-way bank aliasing, free), reduces, activates all 4 gates, updates its
//   own c,h in registers. No second barrier, no second LDS round-trip:
//   double-buffered pbuf makes the single barrier race-free.
__global__ __launch_bounds__(256, 1) __attribute__((amdgpu_waves_per_eu(1)))
void lstm_kernel(
    const float* __restrict__ xz, const float* __restrict__ W_hh,
    const float* __restrict__ W1, const float* __restrict__ W2,
    const float* __restrict__ b2, float* __restrict__ out) {
    __shared__ __align__(16) float pbuf[2][4][G4];   // [parity][k-chunk][gate]
    __shared__ float hfin[HID];
    __shared__ float hbuf[32];
    const int tid = threadIdx.x;
    const int l   = tid & 63;
    const int wv  = tid >> 6;
    const int sb  = __builtin_amdgcn_readfirstlane(16 * wv);   // k-chunk base

    // weights: rows 4l..4l+3, cols [sb, sb+16) -> 16 float4s, pinned resident
    const float* Wb = W_hh + (4 * l) * HID + sb;     // row stride 64 floats
    float4 w00 = *(const float4*)(Wb +   0), w01 = *(const float4*)(Wb +   4),
           w02 = *(const float4*)(Wb +   8), w03 = *(const float4*)(Wb +  12);
    float4 w10 = *(const float4*)(Wb +  64), w11 = *(const float4*)(Wb +  68),
           w12 = *(const float4*)(Wb +  72), w13 = *(const float4*)(Wb +  76);
    float4 w20 = *(const float4*)(Wb + 128), w21 = *(const float4*)(Wb + 132),
           w22 = *(const float4*)(Wb + 136), w23 = *(const float4*)(Wb + 140);
    float4 w30 = *(const float4*)(Wb + 192), w31 = *(const float4*)(Wb + 196),
           w32 = *(const float4*)(Wb + 200), w33 = *(const float4*)(Wb + 204);

#define PIN4(v) asm volatile("" : "+v"(v.x), "+v"(v.y), "+v"(v.z), "+v"(v.w))
    PIN4(w00); PIN4(w01); PIN4(w02); PIN4(w03);
    PIN4(w10); PIN4(w11); PIN4(w12); PIN4(w13);
    PIN4(w20); PIN4(w21); PIN4(w22); PIN4(w23);
    PIN4(w30); PIN4(w31); PIN4(w32); PIN4(w33);
#undef PIN4

    float h = 0.0f, c = 0.0f;       // lane l of every wave: h[l], c[l]

    // per-thread xz columns: the 4 gates of hidden unit l (coalesced per wave)
    const float* zi = xz + l;
    float4 zcur[PF], znxt[PF];
#pragma unroll
    for (int p = 0; p < PF; ++p) {
        const float* r = zi + (size_t)p * G4;
        zcur[p] = make_float4(r[0], r[64], r[128], r[192]);
        znxt[p] = make_float4(0.f, 0.f, 0.f, 0.f);
    }

#define STEP_J4(J4, W0, W1_, W2_, W3_)                                          \
    {   float hx0 = bcast(h, sb + 4 * J4 + 0);                                  \
        float hx1 = bcast(h, sb + 4 * J4 + 1);                                  \
        float hx2 = bcast(h, sb + 4 * J4 + 2);                                  \
        float hx3 = bcast(h, sb + 4 * J4 + 3);                                  \
        a0 = fmaf(W0.x, hx0, a0); a0 = fmaf(W0.y, hx1, a0);                     \
        a0 = fmaf(W0.z, hx2, a0); a0 = fmaf(W0.w, hx3, a0);                     \
        a1 = fmaf(W1_.x, hx0, a1); a1 = fmaf(W1_.y, hx1, a1);                   \
        a1 = fmaf(W1_.z, hx2, a1); a1 = fmaf(W1_.w, hx3, a1);                   \
        a2 = fmaf(W2_.x, hx0, a2); a2 = fmaf(W2_.y, hx1, a2);                   \
        a2 = fmaf(W2_.z, hx2, a2); a2 = fmaf(W2_.w, hx3, a2);                   \
        a3 = fmaf(W3_.x, hx0, a3); a3 = fmaf(W3_.y, hx1, a3);                   \
        a3 = fmaf(W3_.z, hx2, a3); a3 = fmaf(W3_.w, hx3, a3); }

    for (int tb = 0; tb < T_STEPS; tb += PF) {
        if (tb + PF < T_STEPS) {
#pragma unroll
            for (int p = 0; p < PF; ++p) {
                const float* r = zi + (size_t)(tb + PF + p) * G4;
                znxt[p] = make_float4(r[0], r[64], r[128], r[192]);
            }
        }
#pragma unroll
        for (int u = 0; u < PF; ++u) {
            const int par = u & 1;
            // phase 1: partial dots for gates 4l..4l+3 over k-chunk [sb, sb+16)
            float a0 = 0.f, a1 = 0.f, a2 = 0.f, a3 = 0.f;
            STEP_J4(0, w00, w10, w20, w30)
            STEP_J4(1, w01, w11, w21, w31)
            STEP_J4(2, w02, w12, w22, w32)
            STEP_J4(3, w03, w13, w23, w33)
            *(float4*)(&pbuf[par][wv][4 * l]) = make_float4(a0, a1, a2, a3);
            __syncthreads();

            // phase 2: reduce + activate all 4 gates of hidden unit l, update c,h
            const float* pb = &pbuf[par][0][0];
            float si = zcur[u].x + ((pb[l]       + pb[G4 + l])       + (pb[2*G4 + l]       + pb[3*G4 + l]));
            float sf = zcur[u].y + ((pb[64 + l]  + pb[G4 + 64 + l])  + (pb[2*G4 + 64 + l]  + pb[3*G4 + 64 + l]));
            float sg = zcur[u].z + ((pb[128 + l] + pb[G4 + 128 + l]) + (pb[2*G4 + 128 + l] + pb[3*G4 + 128 + l]));
            float so = zcur[u].w + ((pb[192 + l] + pb[G4 + 192 + l]) + (pb[2*G4 + 192 + l] + pb[3*G4 + 192 + l]));
            float ig = sigmoid_f(si);
            float fg = sigmoid_f(sf);
            float gg = tanh_f(sg);
            float og = sigmoid_f(so);
            c = fmaf(fg, c, ig * gg);
            h = og * tanh_f(c);
        }
#pragma unroll
        for (int p = 0; p < PF; ++p) zcur[p] = znxt[p];
    }
#undef STEP_J4

    // head: out = W2 @ relu(W1 @ relu(h_T)) + b2
    if (tid < HID) hfin[tid] = h;
    __syncthreads();
    if (tid < 32) {
        float s = 0.0f;
#pragma unroll
        for (int j = 0; j < HID; ++j) s += W1[tid * HID + j] * fmaxf(hfin[j], 0.0f);
        hbuf[tid] = fmaxf(s, 0.0f);
    }
    __syncthreads();
    if (tid < 3) {
        float s = b2[tid];
#pragma unroll
        for (int j = 0; j < 32; ++j) s += W2[tid * 32 + j] * hbuf[j];
        out[tid] = s;
    }
}

extern "C" void kernel_launch(void* const* d_in, const int* in_sizes, int n_in,
                              void* d_out, int out_size, void* d_ws, size_t ws_size,
                              hipStream_t stream) {
    const float* x   = (const float*)d_in[0];
    const float* Wih = (const float*)d_in[1];
    const float* Whh = (const float*)d_in[2];
    const float* bih = (const float*)d_in[3];
    const float* bhh = (const float*)d_in[4];
    const float* W1  = (const float*)d_in[5];
    const float* W2  = (const float*)d_in[6];
    const float* b2  = (const float*)d_in[7];
    float* out = (float*)d_out;
    float* xz  = (float*)d_ws;   // T_STEPS * 256 floats = 64 MB

    xz_kernel<<<T_STEPS / TS, 256, 0, stream>>>(x, Wih, bih, bhh, xz);
    lstm_kernel<<<1, 256, 0, stream>>>(xz, Whh, W1, W2, b2, out);
}

// Round 7
// 22909.216 us; speedup vs baseline: 1.1321x; 1.1321x over previous
//
#include <hip/hip_runtime.h>

#define T_STEPS 65536
#define NIN 99
#define HID 64
#define G4 256   // 4*HID gates
#define TS 128   // timesteps per block in the projection kernel
#define PF 8     // prefetch depth (steps) in the recurrence kernel

__device__ __forceinline__ float frcp(float x) { return __builtin_amdgcn_rcpf(x); }
__device__ __forceinline__ float fexp(float x) { return __expf(x); }
__device__ __forceinline__ float sigmoid_f(float x) { return frcp(1.0f + fexp(-x)); }
__device__ __forceinline__ float tanh_f(float x) {
    float ax = fabsf(x);
    float e  = fexp(2.0f * ax);                 // inf for large ax fine: rcp(inf)=0
    float r  = 1.0f - 2.0f * frcp(e + 1.0f);
    return copysignf(r, x);
}
// wave-uniform broadcast of lane `lane`'s value via readlane (VALU->SGPR)
__device__ __forceinline__ float bcast(float v, int lane) {
    return __int_as_float(__builtin_amdgcn_readlane(__float_as_int(v), lane));
}

// LDS-only barrier: waits ds/smem (lgkmcnt) but leaves global loads (vmcnt)
// in flight across the barrier. __syncthreads() would drain vmcnt(0) and
// kill the xz prefetch every step (R6 post-mortem).
#define BAR_LGKM() asm volatile("s_waitcnt lgkmcnt(0)\n\ts_barrier" ::: "memory")

// ---------------- Kernel 1: xz2[t][unit][4] = gates (i,f,g,o) of unit ----------------
__global__ __launch_bounds__(256, 1) void xz_kernel(
    const float* __restrict__ x, const float* __restrict__ W_ih,
    const float* __restrict__ b_ih, const float* __restrict__ b_hh,
    float* __restrict__ xz2) {
    __shared__ __align__(16) float xs[TS * 100];   // padded rows: 400 B stride
    const int g  = threadIdx.x;                    // gate row 0..255
    const int t0 = blockIdx.x * TS;
    const int unit = g & 63, d = g >> 6;           // transposed write position

    for (int i = g; i < TS * NIN; i += 256) {
        int tl = i / NIN;
        int j  = i - tl * NIN;
        xs[tl * 100 + j] = x[(size_t)t0 * NIN + i];
    }

    float w[NIN];
#pragma unroll
    for (int j = 0; j < NIN; ++j) w[j] = W_ih[g * NIN + j];
    const float bias = b_ih[g] + b_hh[g];
    __syncthreads();

    for (int tl = 0; tl < TS; ++tl) {
        const float* xr = &xs[tl * 100];
        float a0 = bias, a1 = 0.f, a2 = 0.f, a3 = 0.f;
#pragma unroll
        for (int j4 = 0; j4 < 24; ++j4) {
            float4 xv = *(const float4*)(xr + 4 * j4);
            a0 = fmaf(w[4 * j4 + 0], xv.x, a0);
            a1 = fmaf(w[4 * j4 + 1], xv.y, a1);
            a2 = fmaf(w[4 * j4 + 2], xv.z, a2);
            a3 = fmaf(w[4 * j4 + 3], xv.w, a3);
        }
        a0 = fmaf(w[96], xr[96], a0);
        a1 = fmaf(w[97], xr[97], a1);
        a2 = fmaf(w[98], xr[98], a2);
        xz2[(size_t)(t0 + tl) * G4 + unit * 4 + d] = (a0 + a1) + (a2 + a3);
    }
}

// ---------------- Kernel 2: split-K LSTM, unit-major, lgkm-only barrier ----------------
// Phase 1: thread (wv,l) computes the 4 gates (i,f,g,o) OF UNIT l over k-chunk
//   [16wv,16wv+16): 16 readlane + 64 fma; writes one float4 partial.
// BAR_LGKM (global prefetch stays in flight).
// Phase 2 (replicated): lane l reads the OTHER 3 chunks' float4 partials
//   (3 overlapping ds_read_b128), reduces with its own in-register partial,
//   activates, updates its own c,h. Every wave ends with identical h[l] in
//   lane l -> next phase 1's readlane needs no further exchange.
__global__ __launch_bounds__(256, 1) __attribute__((amdgpu_waves_per_eu(1)))
void lstm_kernel(
    const float* __restrict__ xz2, const float* __restrict__ W_hh,
    const float* __restrict__ W1, const float* __restrict__ W2,
    const float* __restrict__ b2, float* __restrict__ out) {
    __shared__ __align__(16) float4 pbuf[2][4][HID];   // [parity][k-chunk][unit]
    __shared__ float hfin[HID];
    __shared__ float hbuf[32];
    const int tid = threadIdx.x;
    const int l   = tid & 63;
    const int wv  = tid >> 6;
    const int sb  = __builtin_amdgcn_readfirstlane(16 * wv);   // k-chunk base

    // weights: rows l (i), 64+l (f), 128+l (g), 192+l (o); cols [sb, sb+16)
    const float* Wb = W_hh + l * HID + sb;
    float4 wi0 = *(const float4*)(Wb +     0), wi1 = *(const float4*)(Wb +     4),
           wi2 = *(const float4*)(Wb +     8), wi3 = *(const float4*)(Wb +    12);
    float4 wf0 = *(const float4*)(Wb +  4096), wf1 = *(const float4*)(Wb +  4100),
           wf2 = *(const float4*)(Wb +  4104), wf3 = *(const float4*)(Wb +  4108);
    float4 wg0 = *(const float4*)(Wb +  8192), wg1 = *(const float4*)(Wb +  8196),
           wg2 = *(const float4*)(Wb +  8200), wg3 = *(const float4*)(Wb +  8204);
    float4 wo0 = *(const float4*)(Wb + 12288), wo1 = *(const float4*)(Wb + 12292),
           wo2 = *(const float4*)(Wb + 12296), wo3 = *(const float4*)(Wb + 12300);

#define PIN4(v) asm volatile("" : "+v"(v.x), "+v"(v.y), "+v"(v.z), "+v"(v.w))
    PIN4(wi0); PIN4(wi1); PIN4(wi2); PIN4(wi3);
    PIN4(wf0); PIN4(wf1); PIN4(wf2); PIN4(wf3);
    PIN4(wg0); PIN4(wg1); PIN4(wg2); PIN4(wg3);
    PIN4(wo0); PIN4(wo1); PIN4(wo2); PIN4(wo3);
#undef PIN4

    float h = 0.0f, c = 0.0f;       // lane l of every wave: h[l], c[l]

    // xz columns: unit l's 4 gates contiguous -> one dwordx4; wave 0 only
    const float* zi = xz2 + 4 * l;
    float4 zcur[PF], znxt[PF];
    if (wv == 0) {
#pragma unroll
        for (int p = 0; p < PF; ++p) zcur[p] = *(const float4*)(zi + (size_t)p * G4);
    }

#define STEP_J4(J4, WI, WF, WG, WO)                                             \
    {   float hx0 = bcast(h, sb + 4 * J4 + 0);                                  \
        float hx1 = bcast(h, sb + 4 * J4 + 1);                                  \
        float hx2 = bcast(h, sb + 4 * J4 + 2);                                  \
        float hx3 = bcast(h, sb + 4 * J4 + 3);                                  \
        ai = fmaf(WI.x, hx0, ai); ai = fmaf(WI.y, hx1, ai);                     \
        ai = fmaf(WI.z, hx2, ai); ai = fmaf(WI.w, hx3, ai);                     \
        af = fmaf(WF.x, hx0, af); af = fmaf(WF.y, hx1, af);                     \
        af = fmaf(WF.z, hx2, af); af = fmaf(WF.w, hx3, af);                     \
        ag = fmaf(WG.x, hx0, ag); ag = fmaf(WG.y, hx1, ag);                     \
        ag = fmaf(WG.z, hx2, ag); ag = fmaf(WG.w, hx3, ag);                     \
        ao = fmaf(WO.x, hx0, ao); ao = fmaf(WO.y, hx1, ao);                     \
        ao = fmaf(WO.z, hx2, ao); ao = fmaf(WO.w, hx3, ao); }

    for (int tb = 0; tb < T_STEPS; tb += PF) {
        if (wv == 0 && tb + PF < T_STEPS) {
#pragma unroll
            for (int p = 0; p < PF; ++p)
                znxt[p] = *(const float4*)(zi + (size_t)(tb + PF + p) * G4);
        }
#pragma unroll
        for (int u = 0; u < PF; ++u) {
            const int par = u & 1;
            // phase 1: 4 gates of unit l over k-chunk [sb, sb+16)
            float ai, af, ag, ao;
            if (wv == 0) { ai = zcur[u].x; af = zcur[u].y; ag = zcur[u].z; ao = zcur[u].w; }
            else         { ai = 0.f; af = 0.f; ag = 0.f; ao = 0.f; }
            STEP_J4(0, wi0, wf0, wg0, wo0)
            STEP_J4(1, wi1, wf1, wg1, wo1)
            STEP_J4(2, wi2, wf2, wg2, wo2)
            STEP_J4(3, wi3, wf3, wg3, wo3)
            pbuf[par][wv][l] = make_float4(ai, af, ag, ao);
            BAR_LGKM();

            // phase 2: own partial (regs) + other 3 chunks (3x ds_read_b128)
            float4 r0 = pbuf[par][(wv + 1) & 3][l];
            float4 r1 = pbuf[par][(wv + 2) & 3][l];
            float4 r2 = pbuf[par][(wv + 3) & 3][l];
            float si = (ai + r0.x) + (r1.x + r2.x);
            float sf = (af + r0.y) + (r1.y + r2.y);
            float sg = (ag + r0.z) + (r1.z + r2.z);
            float so = (ao + r0.w) + (r1.w + r2.w);
            float ig = sigmoid_f(si);
            float fg = sigmoid_f(sf);
            float gg = tanh_f(sg);
            float og = sigmoid_f(so);
            c = fmaf(fg, c, ig * gg);
            h = og * tanh_f(c);
        }
        if (wv == 0) {
#pragma unroll
            for (int p = 0; p < PF; ++p) zcur[p] = znxt[p];
        }
    }
#undef STEP_J4

    // head: out = W2 @ relu(W1 @ relu(h_T)) + b2
    if (tid < HID) hfin[tid] = h;
    __syncthreads();
    if (tid < 32) {
        float s = 0.0f;
#pragma unroll
        for (int j = 0; j < HID; ++j) s += W1[tid * HID + j] * fmaxf(hfin[j], 0.0f);
        hbuf[tid] = fmaxf(s, 0.0f);
    }
    __syncthreads();
    if (tid < 3) {
        float s = b2[tid];
#pragma unroll
        for (int j = 0; j < 32; ++j) s += W2[tid * 32 + j] * hbuf[j];
        out[tid] = s;
    }
}

extern "C" void kernel_launch(void* const* d_in, const int* in_sizes, int n_in,
                              void* d_out, int out_size, void* d_ws, size_t ws_size,
                              hipStream_t stream) {
    const float* x   = (const float*)d_in[0];
    const float* Wih = (const float*)d_in[1];
    const float* Whh = (const float*)d_in[2];
    const float* bih = (const float*)d_in[3];
    const float* bhh = (const float*)d_in[4];
    const float* W1  = (const float*)d_in[5];
    const float* W2  = (const float*)d_in[6];
    const float* b2  = (const float*)d_in[7];
    float* out = (float*)d_out;
    float* xz2 = (float*)d_ws;   // T_STEPS * 256 floats = 64 MB (transposed layout)

    xz_kernel<<<T_STEPS / TS, 256, 0, stream>>>(x, Wih, bih, bhh, xz2);
    lstm_kernel<<<1, 256, 0, stream>>>(xz2, Whh, W1, W2, b2, out);
}